// Round 2
// baseline (949.539 us; speedup 1.0000x reference)
//
#include <hip/hip_runtime.h>

typedef _Float16 half8  __attribute__((ext_vector_type(8)));
typedef _Float16 half4v __attribute__((ext_vector_type(4)));
typedef _Float16 half2v __attribute__((ext_vector_type(2)));
typedef float    f32x4  __attribute__((ext_vector_type(4)));

#define GAT_SLOPE 0.2f
#define N_SRC0 500000
#define N_DST0 65536
#define N_DST1 8192
#define E0 1048576
#define E1 131072

__device__ __forceinline__ float leaky(float x) { return x >= 0.f ? x : GAT_SLOPE * x; }

// out[k*4+h] = sum_d W[k*(4D) + h*D + d] * a[h*D + d]
__global__ void collapse_kernel(const float* __restrict__ W, const float* __restrict__ a,
                                float* __restrict__ out, int K, int D) {
  int i = blockIdx.x * 256 + threadIdx.x;
  if (i >= K * 4) return;
  int k = i >> 2, h = i & 3;
  int N = 4 * D;
  float s = 0.f;
  for (int d = 0; d < D; ++d) s += W[(size_t)k * N + h * D + d] * a[h * D + d];
  out[i] = s;
}

// WT[n*K+k] = (n < N) ? (fp16)W[k*N+n] : 0   (NT rows total)
__global__ void transposeW_kernel(const float* __restrict__ W, _Float16* __restrict__ WT,
                                  int K, int N, int NT) {
  int i = blockIdx.x * 256 + threadIdx.x;
  if (i >= NT * K) return;
  int nrow = i / K, k = i - nrow * K;
  WT[i] = (nrow < N) ? (_Float16)W[(size_t)k * N + nrow] : (_Float16)0.f;
}

// one wave per node: convert x row (128 fp32) -> fp16, compute el (all) / er (n<n_dst)
__global__ __launch_bounds__(256) void cvt_el_er_kernel(
    const float* __restrict__ x, _Float16* __restrict__ xh,
    const float* __restrict__ wl, const float* __restrict__ wr,
    float* __restrict__ el, float* __restrict__ er, int n_nodes, int n_dst) {
  int n = blockIdx.x * 4 + (threadIdx.x >> 6);
  int lane = threadIdx.x & 63;
  if (n >= n_nodes) return;
  float2 xv = *(const float2*)(x + (size_t)n * 128 + 2 * lane);
  half2v hv = { (_Float16)xv.x, (_Float16)xv.y };
  *(half2v*)(xh + (size_t)n * 128 + 2 * lane) = hv;

  float4 wa = *(const float4*)(wl + 8 * lane);
  float4 wb = *(const float4*)(wl + 8 * lane + 4);
  float p0 = xv.x * wa.x + xv.y * wb.x;
  float p1 = xv.x * wa.y + xv.y * wb.y;
  float p2 = xv.x * wa.z + xv.y * wb.z;
  float p3 = xv.x * wa.w + xv.y * wb.w;
  for (int off = 32; off; off >>= 1) {
    p0 += __shfl_xor(p0, off); p1 += __shfl_xor(p1, off);
    p2 += __shfl_xor(p2, off); p3 += __shfl_xor(p3, off);
  }
  if (lane == 0) {
    el[(size_t)n * 4 + 0] = p0; el[(size_t)n * 4 + 1] = p1;
    el[(size_t)n * 4 + 2] = p2; el[(size_t)n * 4 + 3] = p3;
  }
  if (n < n_dst) {
    float4 ra = *(const float4*)(wr + 8 * lane);
    float4 rb = *(const float4*)(wr + 8 * lane + 4);
    float q0 = xv.x * ra.x + xv.y * rb.x;
    float q1 = xv.x * ra.y + xv.y * rb.y;
    float q2 = xv.x * ra.z + xv.y * rb.z;
    float q3 = xv.x * ra.w + xv.y * rb.w;
    for (int off = 32; off; off >>= 1) {
      q0 += __shfl_xor(q0, off); q1 += __shfl_xor(q1, off);
      q2 += __shfl_xor(q2, off); q3 += __shfl_xor(q3, off);
    }
    if (lane == 0) {
      er[(size_t)n * 4 + 0] = q0; er[(size_t)n * 4 + 1] = q1;
      er[(size_t)n * 4 + 2] = q2; er[(size_t)n * 4 + 3] = q3;
    }
  }
}

// seg[d] = first edge index with dst >= d ; seg[nseg] = E (dst sorted ascending)
__global__ void seg_starts_kernel(const int* __restrict__ dst, int E, int nseg,
                                  int* __restrict__ seg) {
  int i = blockIdx.x * 256 + threadIdx.x;
  if (i > E) return;
  int lo = (i == 0) ? 0 : dst[i - 1] + 1;
  int hi = (i == E) ? nseg : dst[i];
  for (int d = lo; d <= hi; ++d) seg[d] = i;
}

// C(M x 256 fp16) = A(M x K fp16) @ BT(256 x K fp16)^T ; K in {128,256}; 128x128 tile
__global__ __launch_bounds__(256, 2) void gemm_fs_kernel(
    const _Float16* __restrict__ A, const _Float16* __restrict__ BT,
    _Float16* __restrict__ C, int M, int K) {
  __shared__ _Float16 As[128 * 128];
  __shared__ _Float16 Bs[128 * 128];
  const int t = threadIdx.x, lane = t & 63, wid = t >> 6;
  const int m0 = blockIdx.x * 128, n0 = blockIdx.y * 128;
  const int wm = (wid >> 1) * 64, wn = (wid & 1) * 64;
  f32x4 acc[4][4] = {};
  for (int k0 = 0; k0 < K; k0 += 128) {
    // stage 128 rows x 128 halfs for A and B: 2048 chunks of 8 halfs each
    for (int i = 0; i < 8; ++i) {
      int c = t + 256 * i;
      int row = c >> 4;        // 128 rows
      int j = c & 15;          // 16 chunks of 8 halfs per row
      int sw = ((j ^ (row & 7)) << 3);
      half8 va = {};
      int gr = m0 + row;
      if (gr < M) va = *(const half8*)(A + (size_t)gr * K + k0 + j * 8);
      *(half8*)(&As[row * 128 + sw]) = va;
      half8 vb = *(const half8*)(BT + (size_t)(n0 + row) * K + k0 + j * 8);
      *(half8*)(&Bs[row * 128 + sw]) = vb;
    }
    __syncthreads();
    for (int ks = 0; ks < 4; ++ks) {
      int kc = ks * 4 + (lane >> 4);
      half8 af[4], bf[4];
      for (int i = 0; i < 4; ++i) {
        int ra = wm + 16 * i + (lane & 15);
        af[i] = *(const half8*)(&As[ra * 128 + ((kc ^ (ra & 7)) << 3)]);
        int rb = wn + 16 * i + (lane & 15);
        bf[i] = *(const half8*)(&Bs[rb * 128 + ((kc ^ (rb & 7)) << 3)]);
      }
      for (int i = 0; i < 4; ++i)
        for (int j2 = 0; j2 < 4; ++j2)
          acc[i][j2] = __builtin_amdgcn_mfma_f32_16x16x32_f16(af[i], bf[j2], acc[i][j2], 0, 0, 0);
    }
    __syncthreads();
  }
  for (int i = 0; i < 4; ++i)
    for (int j2 = 0; j2 < 4; ++j2) {
      int col = n0 + wn + 16 * j2 + (lane & 15);
      int r0 = m0 + wm + 16 * i + ((lane >> 4) << 2);
      for (int r = 0; r < 4; ++r) {
        int row = r0 + r;
        if (row < M) C[(size_t)row * 256 + col] = (_Float16)acc[i][j2][r];
      }
    }
}

// layer-0 aggregation: one block (128 thr) per dst node; thread owns channels 2t,2t+1
__global__ __launch_bounds__(128) void agg0_kernel(
    const int* __restrict__ src, const int* __restrict__ seg,
    const float* __restrict__ el, const float* __restrict__ er,
    const _Float16* __restrict__ fs, const float* __restrict__ b,
    _Float16* __restrict__ hout) {
  int n = blockIdx.x;
  int t = threadIdx.x, lane = t & 63, w = t >> 6;
  __shared__ float sm[4], sinv[4];
  int s0 = seg[n], s1 = seg[n + 1];
  for (int h = w; h < 4; h += 2) {
    float erv = er[(size_t)n * 4 + h];
    float mx = -__builtin_inff();
    for (int i = s0 + lane; i < s1; i += 64)
      mx = fmaxf(mx, leaky(el[(size_t)src[i] * 4 + h] + erv));
    for (int off = 32; off; off >>= 1) mx = fmaxf(mx, __shfl_xor(mx, off));
    float sum = 0.f;
    for (int i = s0 + lane; i < s1; i += 64)
      sum += __expf(leaky(el[(size_t)src[i] * 4 + h] + erv) - mx);
    for (int off = 32; off; off >>= 1) sum += __shfl_xor(sum, off);
    if (lane == 0) { sm[h] = mx; sinv[h] = 1.f / sum; }
  }
  __syncthreads();
  int c = 2 * t;
  int h = c >> 6;
  float m = sm[h], inv = sinv[h];
  float erv = er[(size_t)n * 4 + h];
  float a0 = 0.f, a1 = 0.f;
  for (int i = s0; i < s1; ++i) {
    int sidx = src[i];
    float e = leaky(el[(size_t)sidx * 4 + h] + erv);
    float al_ = __expf(e - m) * inv;
    half2v f = *(const half2v*)(fs + (size_t)sidx * 256 + c);
    a0 += al_ * (float)f[0];
    a1 += al_ * (float)f[1];
  }
  a0 = fmaxf(a0 + b[c], 0.f);
  a1 = fmaxf(a1 + b[c + 1], 0.f);
  half2v o = { (_Float16)a0, (_Float16)a1 };
  *(half2v*)(hout + (size_t)n * 256 + c) = o;
}

// el1 (all 65536) / er1 (first 8192) from h0 fp16 rows (256 wide)
__global__ __launch_bounds__(256) void el_er1_kernel(
    const _Float16* __restrict__ hsrc, const float* __restrict__ wl,
    const float* __restrict__ wr, float* __restrict__ el, float* __restrict__ er,
    int n_nodes, int n_dst) {
  int n = blockIdx.x * 4 + (threadIdx.x >> 6);
  int lane = threadIdx.x & 63;
  if (n >= n_nodes) return;
  half4v hv = *(const half4v*)(hsrc + (size_t)n * 256 + 4 * lane);
  float xv[4] = { (float)hv[0], (float)hv[1], (float)hv[2], (float)hv[3] };
  float p[4] = {0.f, 0.f, 0.f, 0.f};
  for (int j = 0; j < 4; ++j) {
    float4 wv = *(const float4*)(wl + (4 * lane + j) * 4);
    p[0] += xv[j] * wv.x; p[1] += xv[j] * wv.y;
    p[2] += xv[j] * wv.z; p[3] += xv[j] * wv.w;
  }
  for (int off = 32; off; off >>= 1)
    for (int h = 0; h < 4; ++h) p[h] += __shfl_xor(p[h], off);
  if (lane == 0)
    for (int h = 0; h < 4; ++h) el[(size_t)n * 4 + h] = p[h];
  if (n < n_dst) {
    float q[4] = {0.f, 0.f, 0.f, 0.f};
    for (int j = 0; j < 4; ++j) {
      float4 wv = *(const float4*)(wr + (4 * lane + j) * 4);
      q[0] += xv[j] * wv.x; q[1] += xv[j] * wv.y;
      q[2] += xv[j] * wv.z; q[3] += xv[j] * wv.w;
    }
    for (int off = 32; off; off >>= 1)
      for (int h = 0; h < 4; ++h) q[h] += __shfl_xor(q[h], off);
    if (lane == 0)
      for (int h = 0; h < 4; ++h) er[(size_t)n * 4 + h] = q[h];
  }
}

// layer-1 aggregation + head-mean + log_softmax(47). block = 192 thr per dst node.
__global__ __launch_bounds__(192) void agg1_kernel(
    const int* __restrict__ src, const int* __restrict__ seg,
    const float* __restrict__ el, const float* __restrict__ er,
    const _Float16* __restrict__ fs, const float* __restrict__ b,
    float* __restrict__ out) {
  int n = blockIdx.x;
  int t = threadIdx.x, lane = t & 63, w = t >> 6;
  __shared__ float sm[4], sinv[4];
  __shared__ float row[188];
  int s0 = seg[n], s1 = seg[n + 1];
  for (int h = w; h < 4; h += 3) {
    float erv = er[(size_t)n * 4 + h];
    float mx = -__builtin_inff();
    for (int i = s0 + lane; i < s1; i += 64)
      mx = fmaxf(mx, leaky(el[(size_t)src[i] * 4 + h] + erv));
    for (int off = 32; off; off >>= 1) mx = fmaxf(mx, __shfl_xor(mx, off));
    float sum = 0.f;
    for (int i = s0 + lane; i < s1; i += 64)
      sum += __expf(leaky(el[(size_t)src[i] * 4 + h] + erv) - mx);
    for (int off = 32; off; off >>= 1) sum += __shfl_xor(sum, off);
    if (lane == 0) { sm[h] = mx; sinv[h] = 1.f / sum; }
  }
  __syncthreads();
  int c = t;
  if (c < 188) {
    int h = c / 47;
    float m = sm[h], inv = sinv[h];
    float erv = er[(size_t)n * 4 + h];
    float a = 0.f;
    for (int i = s0; i < s1; ++i) {
      int sidx = src[i];
      float e = leaky(el[(size_t)sidx * 4 + h] + erv);
      a += __expf(e - m) * inv * (float)fs[(size_t)sidx * 256 + c];
    }
    row[c] = a + b[c];
  }
  __syncthreads();
  if (w == 0) {
    float mv = 0.f, v = -__builtin_inff();
    if (lane < 47) {
      mv = 0.25f * (row[lane] + row[lane + 47] + row[lane + 94] + row[lane + 141]);
      v = mv;
    }
    float mx = v;
    for (int off = 32; off; off >>= 1) mx = fmaxf(mx, __shfl_xor(mx, off));
    float s = (lane < 47) ? __expf(mv - mx) : 0.f;
    for (int off = 32; off; off >>= 1) s += __shfl_xor(s, off);
    float lse = mx + __logf(s);
    if (lane < 47) out[(size_t)n * 47 + lane] = mv - lse;
  }
}

extern "C" void kernel_launch(void* const* d_in, const int* in_sizes, int n_in,
                              void* d_out, int out_size, void* d_ws, size_t ws_size,
                              hipStream_t stream) {
  const float* x   = (const float*)d_in[0];
  const int* src0  = (const int*)d_in[1];
  const int* dst0  = (const int*)d_in[2];
  const int* src1  = (const int*)d_in[3];
  const int* dst1  = (const int*)d_in[4];
  const float* Ws0 = (const float*)d_in[5];
  const float* Wd0 = (const float*)d_in[6];
  const float* al0 = (const float*)d_in[7];
  const float* ar0 = (const float*)d_in[8];
  const float* b0  = (const float*)d_in[9];
  const float* Ws1 = (const float*)d_in[10];
  const float* Wd1 = (const float*)d_in[11];
  const float* al1 = (const float*)d_in[12];
  const float* ar1 = (const float*)d_in[13];
  const float* b1  = (const float*)d_in[14];

  char* w = (char*)d_ws;
  auto alloc = [&](size_t bytes) {
    char* p = w;
    w += (bytes + 255) & ~(size_t)255;
    return p;
  };
  _Float16* xh   = (_Float16*)alloc((size_t)N_SRC0 * 128 * 2);
  _Float16* fs0  = (_Float16*)alloc((size_t)N_SRC0 * 256 * 2);
  _Float16* h0   = (_Float16*)alloc((size_t)N_DST0 * 256 * 2);
  _Float16* fs1  = (_Float16*)alloc((size_t)N_DST0 * 256 * 2);
  float* el0     = (float*)alloc((size_t)N_SRC0 * 4 * 4);
  float* er0     = (float*)alloc((size_t)N_DST0 * 4 * 4);
  float* el1     = (float*)alloc((size_t)N_DST0 * 4 * 4);
  float* er1     = (float*)alloc((size_t)N_DST1 * 4 * 4);
  int* seg0      = (int*)alloc((size_t)(N_DST0 + 1) * 4);
  int* seg1      = (int*)alloc((size_t)(N_DST1 + 1) * 4);
  _Float16* WsT0 = (_Float16*)alloc(256 * 128 * 2);
  _Float16* WsT1 = (_Float16*)alloc(256 * 256 * 2);
  float* wl0     = (float*)alloc(128 * 4 * 4);
  float* wr0     = (float*)alloc(128 * 4 * 4);
  float* wl1     = (float*)alloc(256 * 4 * 4);
  float* wr1     = (float*)alloc(256 * 4 * 4);

  collapse_kernel<<<2, 256, 0, stream>>>(Ws0, al0, wl0, 128, 64);
  collapse_kernel<<<2, 256, 0, stream>>>(Wd0, ar0, wr0, 128, 64);
  collapse_kernel<<<4, 256, 0, stream>>>(Ws1, al1, wl1, 256, 47);
  collapse_kernel<<<4, 256, 0, stream>>>(Wd1, ar1, wr1, 256, 47);
  transposeW_kernel<<<(256 * 128 + 255) / 256, 256, 0, stream>>>(Ws0, WsT0, 128, 256, 256);
  transposeW_kernel<<<(256 * 256 + 255) / 256, 256, 0, stream>>>(Ws1, WsT1, 256, 188, 256);
  cvt_el_er_kernel<<<N_SRC0 / 4, 256, 0, stream>>>(x, xh, wl0, wr0, el0, er0, N_SRC0, N_DST0);
  seg_starts_kernel<<<(E0 + 1 + 255) / 256, 256, 0, stream>>>(dst0, E0, N_DST0, seg0);
  seg_starts_kernel<<<(E1 + 1 + 255) / 256, 256, 0, stream>>>(dst1, E1, N_DST1, seg1);
  gemm_fs_kernel<<<dim3((N_SRC0 + 127) / 128, 2), 256, 0, stream>>>(xh, WsT0, fs0, N_SRC0, 128);
  agg0_kernel<<<N_DST0, 128, 0, stream>>>(src0, seg0, el0, er0, fs0, b0, h0);
  el_er1_kernel<<<N_DST0 / 4, 256, 0, stream>>>(h0, wl1, wr1, el1, er1, N_DST0, N_DST1);
  gemm_fs_kernel<<<dim3(N_DST0 / 128, 2), 256, 0, stream>>>(h0, WsT1, fs1, N_DST0, 256);
  agg1_kernel<<<N_DST1, 192, 0, stream>>>(src1, seg1, el1, er1, fs1, b1, (float*)d_out);
}

// Round 3
// 825.173 us; speedup vs baseline: 1.1507x; 1.1507x over previous
//
#include <hip/hip_runtime.h>

typedef _Float16 half8  __attribute__((ext_vector_type(8)));
typedef _Float16 half2v __attribute__((ext_vector_type(2)));
typedef _Float16 half4v __attribute__((ext_vector_type(4)));
typedef float    f32x4  __attribute__((ext_vector_type(4)));

#define GAT_SLOPE 0.2f
#define N_SRC0 500000
#define N_DST0 65536
#define N_DST1 8192
#define E0 1048576
#define E1 131072

__device__ __forceinline__ float leaky(float x) { return x >= 0.f ? x : GAT_SLOPE * x; }

// out[k*4+h] = sum_d W[k*(4D) + h*D + d] * a[h*D + d]
__global__ void collapse_kernel(const float* __restrict__ W, const float* __restrict__ a,
                                float* __restrict__ out, int K, int D) {
  int i = blockIdx.x * 256 + threadIdx.x;
  if (i >= K * 4) return;
  int k = i >> 2, h = i & 3;
  int N = 4 * D;
  float s = 0.f;
  for (int d = 0; d < D; ++d) s += W[(size_t)k * N + h * D + d] * a[h * D + d];
  out[i] = s;
}

// WT[n*K+k] = (fp16)W[k*N+n]  (plain transpose, N==NT)
__global__ void transposeW_kernel(const float* __restrict__ W, _Float16* __restrict__ WT,
                                  int K, int N) {
  int i = blockIdx.x * 256 + threadIdx.x;
  if (i >= N * K) return;
  int nrow = i / K, k = i - nrow * K;
  WT[i] = (_Float16)W[(size_t)k * N + nrow];
}

// layer-1 transpose with head padding 47 -> 64: output n in [0,256): h=n>>6, d=n&63
// WT[n*K+k] = d<47 ? W[k*188 + h*47 + d] : 0
__global__ void transposeW_pad47_kernel(const float* __restrict__ W, _Float16* __restrict__ WT,
                                        int K) {
  int i = blockIdx.x * 256 + threadIdx.x;
  if (i >= 256 * K) return;
  int n = i / K, k = i - n * K;
  int h = n >> 6, d = n & 63;
  WT[i] = (d < 47) ? (_Float16)W[(size_t)k * 188 + h * 47 + d] : (_Float16)0.f;
}

// er0: one wave per node (first n_dst rows of x): er[n,h] = x[n,:] . wr[:,h]
__global__ __launch_bounds__(256) void er0_kernel(
    const float* __restrict__ x, const float* __restrict__ wr,
    float* __restrict__ er, int n_dst) {
  int n = blockIdx.x * 4 + (threadIdx.x >> 6);
  int lane = threadIdx.x & 63;
  if (n >= n_dst) return;
  float2 xv = *(const float2*)(x + (size_t)n * 128 + 2 * lane);
  float4 ra = *(const float4*)(wr + 8 * lane);
  float4 rb = *(const float4*)(wr + 8 * lane + 4);
  float q0 = xv.x * ra.x + xv.y * rb.x;
  float q1 = xv.x * ra.y + xv.y * rb.y;
  float q2 = xv.x * ra.z + xv.y * rb.z;
  float q3 = xv.x * ra.w + xv.y * rb.w;
  for (int off = 32; off; off >>= 1) {
    q0 += __shfl_xor(q0, off); q1 += __shfl_xor(q1, off);
    q2 += __shfl_xor(q2, off); q3 += __shfl_xor(q3, off);
  }
  if (lane == 0) {
    er[(size_t)n * 4 + 0] = q0; er[(size_t)n * 4 + 1] = q1;
    er[(size_t)n * 4 + 2] = q2; er[(size_t)n * 4 + 3] = q3;
  }
}

// seg[d] = first edge index with dst >= d ; seg[nseg] = E (dst sorted ascending)
__global__ void seg_starts_kernel(const int* __restrict__ dst, int E, int nseg,
                                  int* __restrict__ seg) {
  int i = blockIdx.x * 256 + threadIdx.x;
  if (i > E) return;
  int lo = (i == 0) ? 0 : dst[i - 1] + 1;
  int hi = (i == E) ? nseg : dst[i];
  for (int d = lo; d <= hi; ++d) seg[d] = i;
}

// layer-0 GEMM: C(M x 256 fp16) = A(M x 128 fp32, cvt to fp16) @ BT(256 x 128 fp16)^T
// epilogue: el[row,h] = sum_c C[row,c]*al[c]  (head h = 64-col span of this wave)
// grid (2, nm): n-tile fastest so both n-tiles of an m-tile share the A tile in L2.
__global__ __launch_bounds__(256, 2) void gemm0_kernel(
    const float* __restrict__ A, const _Float16* __restrict__ BT,
    const float* __restrict__ al, _Float16* __restrict__ C,
    float* __restrict__ el, int M) {
  __shared__ _Float16 As[128 * 128];
  __shared__ _Float16 Bs[128 * 128];
  const int t = threadIdx.x, lane = t & 63, wid = t >> 6;
  const int m0 = blockIdx.y * 128, n0 = blockIdx.x * 128;
  const int wm = (wid >> 1) * 64, wn = (wid & 1) * 64;
  f32x4 acc[4][4] = {};
  for (int i = 0; i < 8; ++i) {
    int c = t + 256 * i;
    int row = c >> 4, j = c & 15;
    int sw = ((j ^ (row & 7)) << 3);
    half8 va = {};
    int gr = m0 + row;
    if (gr < M) {
      float4 f0 = *(const float4*)(A + (size_t)gr * 128 + j * 8);
      float4 f1 = *(const float4*)(A + (size_t)gr * 128 + j * 8 + 4);
      va[0] = (_Float16)f0.x; va[1] = (_Float16)f0.y;
      va[2] = (_Float16)f0.z; va[3] = (_Float16)f0.w;
      va[4] = (_Float16)f1.x; va[5] = (_Float16)f1.y;
      va[6] = (_Float16)f1.z; va[7] = (_Float16)f1.w;
    }
    *(half8*)(&As[row * 128 + sw]) = va;
    half8 vb = *(const half8*)(BT + (size_t)(n0 + row) * 128 + j * 8);
    *(half8*)(&Bs[row * 128 + sw]) = vb;
  }
  __syncthreads();
  for (int ks = 0; ks < 4; ++ks) {
    int kc = ks * 4 + (lane >> 4);
    half8 af[4], bf[4];
    for (int i = 0; i < 4; ++i) {
      int ra = wm + 16 * i + (lane & 15);
      af[i] = *(const half8*)(&As[ra * 128 + ((kc ^ (ra & 7)) << 3)]);
      int rb = wn + 16 * i + (lane & 15);
      bf[i] = *(const half8*)(&Bs[rb * 128 + ((kc ^ (rb & 7)) << 3)]);
    }
    for (int i = 0; i < 4; ++i)
      for (int j2 = 0; j2 < 4; ++j2)
        acc[i][j2] = __builtin_amdgcn_mfma_f32_16x16x32_f16(af[i], bf[j2], acc[i][j2], 0, 0, 0);
  }
  // C store
  for (int i = 0; i < 4; ++i)
    for (int j2 = 0; j2 < 4; ++j2) {
      int col = n0 + wn + 16 * j2 + (lane & 15);
      int r0 = m0 + wm + 16 * i + ((lane >> 4) << 2);
      for (int r = 0; r < 4; ++r) {
        int row = r0 + r;
        if (row < M) C[(size_t)row * 256 + col] = (_Float16)acc[i][j2][r];
      }
    }
  // el epilogue
  float alv[4];
  for (int j2 = 0; j2 < 4; ++j2) alv[j2] = al[n0 + wn + 16 * j2 + (lane & 15)];
  int head = (n0 + wn) >> 6;
  for (int i = 0; i < 4; ++i)
    for (int r = 0; r < 4; ++r) {
      float s = acc[i][0][r] * alv[0] + acc[i][1][r] * alv[1] +
                acc[i][2][r] * alv[2] + acc[i][3][r] * alv[3];
      s += __shfl_xor(s, 1); s += __shfl_xor(s, 2);
      s += __shfl_xor(s, 4); s += __shfl_xor(s, 8);
      if ((lane & 15) == 0) {
        int row = m0 + wm + 16 * i + ((lane >> 4) << 2) + r;
        if (row < M) el[(size_t)row * 4 + head] = s;
      }
    }
}

// layer-1 GEMM: C(M x 256 fp16) = A(M x 256 fp16) @ BT(256 x 256 fp16)^T, grid (2, nm)
__global__ __launch_bounds__(256, 2) void gemm_fs_kernel(
    const _Float16* __restrict__ A, const _Float16* __restrict__ BT,
    _Float16* __restrict__ C, int M, int K) {
  __shared__ _Float16 As[128 * 128];
  __shared__ _Float16 Bs[128 * 128];
  const int t = threadIdx.x, lane = t & 63, wid = t >> 6;
  const int m0 = blockIdx.y * 128, n0 = blockIdx.x * 128;
  const int wm = (wid >> 1) * 64, wn = (wid & 1) * 64;
  f32x4 acc[4][4] = {};
  for (int k0 = 0; k0 < K; k0 += 128) {
    for (int i = 0; i < 8; ++i) {
      int c = t + 256 * i;
      int row = c >> 4, j = c & 15;
      int sw = ((j ^ (row & 7)) << 3);
      half8 va = {};
      int gr = m0 + row;
      if (gr < M) va = *(const half8*)(A + (size_t)gr * K + k0 + j * 8);
      *(half8*)(&As[row * 128 + sw]) = va;
      half8 vb = *(const half8*)(BT + (size_t)(n0 + row) * K + k0 + j * 8);
      *(half8*)(&Bs[row * 128 + sw]) = vb;
    }
    __syncthreads();
    for (int ks = 0; ks < 4; ++ks) {
      int kc = ks * 4 + (lane >> 4);
      half8 af[4], bf[4];
      for (int i = 0; i < 4; ++i) {
        int ra = wm + 16 * i + (lane & 15);
        af[i] = *(const half8*)(&As[ra * 128 + ((kc ^ (ra & 7)) << 3)]);
        int rb = wn + 16 * i + (lane & 15);
        bf[i] = *(const half8*)(&Bs[rb * 128 + ((kc ^ (rb & 7)) << 3)]);
      }
      for (int i = 0; i < 4; ++i)
        for (int j2 = 0; j2 < 4; ++j2)
          acc[i][j2] = __builtin_amdgcn_mfma_f32_16x16x32_f16(af[i], bf[j2], acc[i][j2], 0, 0, 0);
    }
    __syncthreads();
  }
  for (int i = 0; i < 4; ++i)
    for (int j2 = 0; j2 < 4; ++j2) {
      int col = n0 + wn + 16 * j2 + (lane & 15);
      int r0 = m0 + wm + 16 * i + ((lane >> 4) << 2);
      for (int r = 0; r < 4; ++r) {
        int row = r0 + r;
        if (row < M) C[(size_t)row * 256 + col] = (_Float16)acc[i][j2][r];
      }
    }
}

// layer-0 aggregation v2: 128 thr/node. Phase1: 2-pass lane-parallel softmax stats.
// Phase2: 4 edge-groups x 32 lanes x 8 ch (half8 loads), xor-32 + LDS reduce.
__global__ __launch_bounds__(128) void agg0_kernel(
    const int* __restrict__ src, const int* __restrict__ seg,
    const float* __restrict__ el, const float* __restrict__ er,
    const _Float16* __restrict__ fs, const float* __restrict__ b,
    _Float16* __restrict__ hout) {
  int n = blockIdx.x;
  int t = threadIdx.x, lane = t & 63, w = t >> 6;
  __shared__ float sm[4], sinv[4];
  __shared__ float part[256];
  int s0 = seg[n], s1 = seg[n + 1];
  for (int h = w; h < 4; h += 2) {
    float erv = er[(size_t)n * 4 + h];
    float mx = -__builtin_inff();
    for (int i = s0 + lane; i < s1; i += 64)
      mx = fmaxf(mx, leaky(el[(size_t)src[i] * 4 + h] + erv));
    for (int off = 32; off; off >>= 1) mx = fmaxf(mx, __shfl_xor(mx, off));
    float sum = 0.f;
    for (int i = s0 + lane; i < s1; i += 64)
      sum += __expf(leaky(el[(size_t)src[i] * 4 + h] + erv) - mx);
    for (int off = 32; off; off >>= 1) sum += __shfl_xor(sum, off);
    if (lane == 0) { sm[h] = mx; sinv[h] = 1.f / sum; }
  }
  __syncthreads();
  int g = t >> 5, ci = t & 31, h = ci >> 3;
  float erv = er[(size_t)n * 4 + h];
  float m = sm[h], inv = sinv[h];
  float acc[8] = {};
  for (int i = s0 + g; i < s1; i += 4) {
    int sidx = src[i];
    float a = __expf(leaky(el[(size_t)sidx * 4 + h] + erv) - m) * inv;
    half8 f = *(const half8*)(fs + (size_t)sidx * 256 + ci * 8);
#pragma unroll
    for (int j = 0; j < 8; ++j) acc[j] += a * (float)f[j];
  }
#pragma unroll
  for (int j = 0; j < 8; ++j) acc[j] += __shfl_xor(acc[j], 32);
  if (w == 1 && lane < 32) {
#pragma unroll
    for (int j = 0; j < 8; ++j) part[ci * 8 + j] = acc[j];
  }
  __syncthreads();
  if (w == 0 && lane < 32) {
    half8 o;
#pragma unroll
    for (int j = 0; j < 8; ++j) {
      float v = acc[j] + part[ci * 8 + j] + b[ci * 8 + j];
      o[j] = (_Float16)fmaxf(v, 0.f);
    }
    *(half8*)(hout + (size_t)n * 256 + ci * 8) = o;
  }
}

// el1 (all 65536) / er1 (first 8192) from h0 fp16 rows (256 wide)
__global__ __launch_bounds__(256) void el_er1_kernel(
    const _Float16* __restrict__ hsrc, const float* __restrict__ wl,
    const float* __restrict__ wr, float* __restrict__ el, float* __restrict__ er,
    int n_nodes, int n_dst) {
  int n = blockIdx.x * 4 + (threadIdx.x >> 6);
  int lane = threadIdx.x & 63;
  if (n >= n_nodes) return;
  half4v hv = *(const half4v*)(hsrc + (size_t)n * 256 + 4 * lane);
  float xv[4] = { (float)hv[0], (float)hv[1], (float)hv[2], (float)hv[3] };
  float p[4] = {0.f, 0.f, 0.f, 0.f};
  for (int j = 0; j < 4; ++j) {
    float4 wv = *(const float4*)(wl + (4 * lane + j) * 4);
    p[0] += xv[j] * wv.x; p[1] += xv[j] * wv.y;
    p[2] += xv[j] * wv.z; p[3] += xv[j] * wv.w;
  }
  for (int off = 32; off; off >>= 1)
    for (int h = 0; h < 4; ++h) p[h] += __shfl_xor(p[h], off);
  if (lane == 0)
    for (int h = 0; h < 4; ++h) el[(size_t)n * 4 + h] = p[h];
  if (n < n_dst) {
    float q[4] = {0.f, 0.f, 0.f, 0.f};
    for (int j = 0; j < 4; ++j) {
      float4 wv = *(const float4*)(wr + (4 * lane + j) * 4);
      q[0] += xv[j] * wv.x; q[1] += xv[j] * wv.y;
      q[2] += xv[j] * wv.z; q[3] += xv[j] * wv.w;
    }
    for (int off = 32; off; off >>= 1)
      for (int h = 0; h < 4; ++h) q[h] += __shfl_xor(q[h], off);
    if (lane == 0)
      for (int h = 0; h < 4; ++h) er[(size_t)n * 4 + h] = q[h];
  }
}

// layer-1 aggregation v2 (head-padded fs1) + head-mean(+bias-mean) + log_softmax(47)
__global__ __launch_bounds__(128) void agg1_kernel(
    const int* __restrict__ src, const int* __restrict__ seg,
    const float* __restrict__ el, const float* __restrict__ er,
    const _Float16* __restrict__ fs, const float* __restrict__ b,
    float* __restrict__ out) {
  int n = blockIdx.x;
  int t = threadIdx.x, lane = t & 63, w = t >> 6;
  __shared__ float sm[4], sinv[4];
  __shared__ float row[256];
  int s0 = seg[n], s1 = seg[n + 1];
  for (int h = w; h < 4; h += 2) {
    float erv = er[(size_t)n * 4 + h];
    float mx = -__builtin_inff();
    for (int i = s0 + lane; i < s1; i += 64)
      mx = fmaxf(mx, leaky(el[(size_t)src[i] * 4 + h] + erv));
    for (int off = 32; off; off >>= 1) mx = fmaxf(mx, __shfl_xor(mx, off));
    float sum = 0.f;
    for (int i = s0 + lane; i < s1; i += 64)
      sum += __expf(leaky(el[(size_t)src[i] * 4 + h] + erv) - mx);
    for (int off = 32; off; off >>= 1) sum += __shfl_xor(sum, off);
    if (lane == 0) { sm[h] = mx; sinv[h] = 1.f / sum; }
  }
  __syncthreads();
  int g = t >> 5, ci = t & 31, h = ci >> 3;
  float erv = er[(size_t)n * 4 + h];
  float m = sm[h], inv = sinv[h];
  float acc[8] = {};
  for (int i = s0 + g; i < s1; i += 4) {
    int sidx = src[i];
    float a = __expf(leaky(el[(size_t)sidx * 4 + h] + erv) - m) * inv;
    half8 f = *(const half8*)(fs + (size_t)sidx * 256 + ci * 8);
#pragma unroll
    for (int j = 0; j < 8; ++j) acc[j] += a * (float)f[j];
  }
#pragma unroll
  for (int j = 0; j < 8; ++j) acc[j] += __shfl_xor(acc[j], 32);
  if (w == 1 && lane < 32) {
#pragma unroll
    for (int j = 0; j < 8; ++j) row[ci * 8 + j] = acc[j];
  }
  __syncthreads();
  if (w == 0 && lane < 32) {
#pragma unroll
    for (int j = 0; j < 8; ++j) row[ci * 8 + j] += acc[j];
  }
  __syncthreads();
  if (w == 0) {
    float mv = 0.f, v = -__builtin_inff();
    if (lane < 47) {
      mv = 0.25f * (row[lane] + row[64 + lane] + row[128 + lane] + row[192 + lane])
         + 0.25f * (b[lane] + b[47 + lane] + b[94 + lane] + b[141 + lane]);
      v = mv;
    }
    float mx = v;
    for (int off = 32; off; off >>= 1) mx = fmaxf(mx, __shfl_xor(mx, off));
    float s = (lane < 47) ? __expf(mv - mx) : 0.f;
    for (int off = 32; off; off >>= 1) s += __shfl_xor(s, off);
    float lse = mx + __logf(s);
    if (lane < 47) out[(size_t)n * 47 + lane] = mv - lse;
  }
}

extern "C" void kernel_launch(void* const* d_in, const int* in_sizes, int n_in,
                              void* d_out, int out_size, void* d_ws, size_t ws_size,
                              hipStream_t stream) {
  const float* x   = (const float*)d_in[0];
  const int* src0  = (const int*)d_in[1];
  const int* dst0  = (const int*)d_in[2];
  const int* src1  = (const int*)d_in[3];
  const int* dst1  = (const int*)d_in[4];
  const float* Ws0 = (const float*)d_in[5];
  const float* Wd0 = (const float*)d_in[6];
  const float* al0 = (const float*)d_in[7];
  const float* ar0 = (const float*)d_in[8];
  const float* b0  = (const float*)d_in[9];
  const float* Ws1 = (const float*)d_in[10];
  const float* Wd1 = (const float*)d_in[11];
  const float* al1 = (const float*)d_in[12];
  const float* ar1 = (const float*)d_in[13];
  const float* b1  = (const float*)d_in[14];

  char* w = (char*)d_ws;
  auto alloc = [&](size_t bytes) {
    char* p = w;
    w += (bytes + 255) & ~(size_t)255;
    return p;
  };
  _Float16* fs0  = (_Float16*)alloc((size_t)N_SRC0 * 256 * 2);
  _Float16* h0   = (_Float16*)alloc((size_t)N_DST0 * 256 * 2);
  _Float16* fs1  = (_Float16*)alloc((size_t)N_DST0 * 256 * 2);
  float* el0     = (float*)alloc((size_t)N_SRC0 * 4 * 4);
  float* er0     = (float*)alloc((size_t)N_DST0 * 4 * 4);
  float* el1     = (float*)alloc((size_t)N_DST0 * 4 * 4);
  float* er1     = (float*)alloc((size_t)N_DST1 * 4 * 4);
  int* seg0      = (int*)alloc((size_t)(N_DST0 + 1) * 4);
  int* seg1      = (int*)alloc((size_t)(N_DST1 + 1) * 4);
  _Float16* WsT0 = (_Float16*)alloc(256 * 128 * 2);
  _Float16* WsT1 = (_Float16*)alloc(256 * 256 * 2);
  float* wr0     = (float*)alloc(128 * 4 * 4);
  float* wl1     = (float*)alloc(256 * 4 * 4);
  float* wr1     = (float*)alloc(256 * 4 * 4);

  collapse_kernel<<<2, 256, 0, stream>>>(Wd0, ar0, wr0, 128, 64);
  collapse_kernel<<<4, 256, 0, stream>>>(Ws1, al1, wl1, 256, 47);
  collapse_kernel<<<4, 256, 0, stream>>>(Wd1, ar1, wr1, 256, 47);
  transposeW_kernel<<<(256 * 128 + 255) / 256, 256, 0, stream>>>(Ws0, WsT0, 128, 256);
  transposeW_pad47_kernel<<<256, 256, 0, stream>>>(Ws1, WsT1, 256);
  er0_kernel<<<N_DST0 / 4, 256, 0, stream>>>(x, wr0, er0, N_DST0);
  seg_starts_kernel<<<(E0 + 1 + 255) / 256, 256, 0, stream>>>(dst0, E0, N_DST0, seg0);
  seg_starts_kernel<<<(E1 + 1 + 255) / 256, 256, 0, stream>>>(dst1, E1, N_DST1, seg1);
  gemm0_kernel<<<dim3(2, (N_SRC0 + 127) / 128), 256, 0, stream>>>(x, WsT0, al0, fs0, el0, N_SRC0);
  agg0_kernel<<<N_DST0, 128, 0, stream>>>(src0, seg0, el0, er0, fs0, b0, h0);
  el_er1_kernel<<<N_DST0 / 4, 256, 0, stream>>>(h0, wl1, wr1, el1, er1, N_DST0, N_DST1);
  gemm_fs_kernel<<<dim3(2, N_DST0 / 128), 256, 0, stream>>>(h0, WsT1, fs1, N_DST0, 256);
  agg1_kernel<<<N_DST1, 128, 0, stream>>>(src1, seg1, el1, er1, fs1, b1, (float*)d_out);
}

// Round 4
// 692.387 us; speedup vs baseline: 1.3714x; 1.1918x over previous
//
#include <hip/hip_runtime.h>

typedef _Float16 half8  __attribute__((ext_vector_type(8)));
typedef _Float16 half4v __attribute__((ext_vector_type(4)));
typedef _Float16 half2v __attribute__((ext_vector_type(2)));
typedef float    f32x4  __attribute__((ext_vector_type(4)));

#define GAT_SLOPE 0.2f
#define N_SRC0 500000
#define N_DST0 65536
#define N_DST1 8192
#define E0 1048576
#define E1 131072

__device__ __forceinline__ float leaky(float x) { return x >= 0.f ? x : GAT_SLOPE * x; }

// out[k*4+h] = sum_d W[k*(4D) + h*D + d] * a[h*D + d]
__global__ void collapse_kernel(const float* __restrict__ W, const float* __restrict__ a,
                                float* __restrict__ out, int K, int D) {
  int i = blockIdx.x * 256 + threadIdx.x;
  if (i >= K * 4) return;
  int k = i >> 2, h = i & 3;
  int N = 4 * D;
  float s = 0.f;
  for (int d = 0; d < D; ++d) s += W[(size_t)k * N + h * D + d] * a[h * D + d];
  out[i] = s;
}

// WT[n*K+k] = (fp16)W[k*N+n]
__global__ void transposeW_kernel(const float* __restrict__ W, _Float16* __restrict__ WT,
                                  int K, int N) {
  int i = blockIdx.x * 256 + threadIdx.x;
  if (i >= N * K) return;
  int nrow = i / K, k = i - nrow * K;
  WT[i] = (_Float16)W[(size_t)k * N + nrow];
}

// BTs[n*1024 + h*256 + k] = (n<47) ? 0.25*Ws1[k*188 + h*47 + n] : 0   (64 x 1024)
__global__ void wstack_kernel(const float* __restrict__ W, _Float16* __restrict__ BTs) {
  int i = blockIdx.x * 256 + threadIdx.x;  // i < 64*1024
  int n = i >> 10, kk = i & 1023;
  int h = kk >> 8, k = kk & 255;
  BTs[i] = (n < 47) ? (_Float16)(0.25f * W[(size_t)k * 188 + h * 47 + n]) : (_Float16)0.f;
}

// one wave per node: x row -> fp16 xh, el0 (all), er0 (n < n_dst)
__global__ __launch_bounds__(256) void cvt_el_er_kernel(
    const float* __restrict__ x, _Float16* __restrict__ xh,
    const float* __restrict__ wl, const float* __restrict__ wr,
    float* __restrict__ el, float* __restrict__ er, int n_nodes, int n_dst) {
  int n = blockIdx.x * 4 + (threadIdx.x >> 6);
  int lane = threadIdx.x & 63;
  if (n >= n_nodes) return;
  float2 xv = *(const float2*)(x + (size_t)n * 128 + 2 * lane);
  half2v hv = { (_Float16)xv.x, (_Float16)xv.y };
  *(half2v*)(xh + (size_t)n * 128 + 2 * lane) = hv;

  float4 wa = *(const float4*)(wl + 8 * lane);
  float4 wb = *(const float4*)(wl + 8 * lane + 4);
  float p0 = xv.x * wa.x + xv.y * wb.x;
  float p1 = xv.x * wa.y + xv.y * wb.y;
  float p2 = xv.x * wa.z + xv.y * wb.z;
  float p3 = xv.x * wa.w + xv.y * wb.w;
  for (int off = 32; off; off >>= 1) {
    p0 += __shfl_xor(p0, off); p1 += __shfl_xor(p1, off);
    p2 += __shfl_xor(p2, off); p3 += __shfl_xor(p3, off);
  }
  if (lane == 0) {
    el[(size_t)n * 4 + 0] = p0; el[(size_t)n * 4 + 1] = p1;
    el[(size_t)n * 4 + 2] = p2; el[(size_t)n * 4 + 3] = p3;
  }
  if (n < n_dst) {
    float4 ra = *(const float4*)(wr + 8 * lane);
    float4 rb = *(const float4*)(wr + 8 * lane + 4);
    float q0 = xv.x * ra.x + xv.y * rb.x;
    float q1 = xv.x * ra.y + xv.y * rb.y;
    float q2 = xv.x * ra.z + xv.y * rb.z;
    float q3 = xv.x * ra.w + xv.y * rb.w;
    for (int off = 32; off; off >>= 1) {
      q0 += __shfl_xor(q0, off); q1 += __shfl_xor(q1, off);
      q2 += __shfl_xor(q2, off); q3 += __shfl_xor(q3, off);
    }
    if (lane == 0) {
      er[(size_t)n * 4 + 0] = q0; er[(size_t)n * 4 + 1] = q1;
      er[(size_t)n * 4 + 2] = q2; er[(size_t)n * 4 + 3] = q3;
    }
  }
}

// el1 (all n_nodes) / er1 (first n_dst) from h0 fp16 rows (256 wide)
__global__ __launch_bounds__(256) void el_er1_kernel(
    const _Float16* __restrict__ hsrc, const float* __restrict__ wl,
    const float* __restrict__ wr, float* __restrict__ el, float* __restrict__ er,
    int n_nodes, int n_dst) {
  int n = blockIdx.x * 4 + (threadIdx.x >> 6);
  int lane = threadIdx.x & 63;
  if (n >= n_nodes) return;
  half4v hv = *(const half4v*)(hsrc + (size_t)n * 256 + 4 * lane);
  float xv[4] = { (float)hv[0], (float)hv[1], (float)hv[2], (float)hv[3] };
  float p[4] = {0.f, 0.f, 0.f, 0.f};
  for (int j = 0; j < 4; ++j) {
    float4 wv = *(const float4*)(wl + (4 * lane + j) * 4);
    p[0] += xv[j] * wv.x; p[1] += xv[j] * wv.y;
    p[2] += xv[j] * wv.z; p[3] += xv[j] * wv.w;
  }
  for (int off = 32; off; off >>= 1)
    for (int h = 0; h < 4; ++h) p[h] += __shfl_xor(p[h], off);
  if (lane == 0)
    for (int h = 0; h < 4; ++h) el[(size_t)n * 4 + h] = p[h];
  if (n < n_dst) {
    float q[4] = {0.f, 0.f, 0.f, 0.f};
    for (int j = 0; j < 4; ++j) {
      float4 wv = *(const float4*)(wr + (4 * lane + j) * 4);
      q[0] += xv[j] * wv.x; q[1] += xv[j] * wv.y;
      q[2] += xv[j] * wv.z; q[3] += xv[j] * wv.w;
    }
    for (int off = 32; off; off >>= 1)
      for (int h = 0; h < 4; ++h) q[h] += __shfl_xor(q[h], off);
    if (lane == 0)
      for (int h = 0; h < 4; ++h) er[(size_t)n * 4 + h] = q[h];
  }
}

// seg[d] = first edge index with dst >= d ; seg[nseg] = E (dst sorted ascending)
__global__ void seg_starts_kernel(const int* __restrict__ dst, int E, int nseg,
                                  int* __restrict__ seg) {
  int i = blockIdx.x * 256 + threadIdx.x;
  if (i > E) return;
  int lo = (i == 0) ? 0 : dst[i - 1] + 1;
  int hi = (i == E) ? nseg : dst[i];
  for (int d = lo; d <= hi; ++d) seg[d] = i;
}

// layer-0 aggregation of RAW features: axh[n][h][0:128] = sum_e alpha[h] * xh[src_e]
// 128 thr/node. Stats: online softmax, wave w handles heads 2w,2w+1.
__global__ __launch_bounds__(128) void agg0x_kernel(
    const int* __restrict__ src, const int* __restrict__ seg,
    const float* __restrict__ el, const float* __restrict__ er,
    const _Float16* __restrict__ xh, _Float16* __restrict__ axh) {
  int n = blockIdx.x;
  int t = threadIdx.x, lane = t & 63, w = t >> 6;
  __shared__ float sm[4], sinv[4];
  __shared__ float part[512];
  int s0 = seg[n], s1 = seg[n + 1];
  float4 erv = *(const float4*)(er + (size_t)n * 4);
  {
    float era = w ? erv.z : erv.x;
    float erb = w ? erv.w : erv.y;
    float ma = -1e30f, mb = -1e30f, sa = 0.f, sb = 0.f;
    for (int i = s0 + lane; i < s1; i += 64) {
      float4 e4 = *(const float4*)(el + (size_t)src[i] * 4);
      float ea = leaky((w ? e4.z : e4.x) + era);
      float eb = leaky((w ? e4.w : e4.y) + erb);
      float mna = fmaxf(ma, ea);
      sa = sa * __expf(ma - mna) + __expf(ea - mna); ma = mna;
      float mnb = fmaxf(mb, eb);
      sb = sb * __expf(mb - mnb) + __expf(eb - mnb); mb = mnb;
    }
    for (int off = 32; off; off >>= 1) {
      float mo = __shfl_xor(ma, off), so = __shfl_xor(sa, off);
      float mn = fmaxf(ma, mo);
      sa = sa * __expf(ma - mn) + so * __expf(mo - mn); ma = mn;
      mo = __shfl_xor(mb, off); so = __shfl_xor(sb, off);
      mn = fmaxf(mb, mo);
      sb = sb * __expf(mb - mn) + so * __expf(mo - mn); mb = mn;
    }
    if (lane == 0) {
      sm[2 * w] = ma; sm[2 * w + 1] = mb;
      sinv[2 * w] = 1.f / sa; sinv[2 * w + 1] = 1.f / sb;
    }
  }
  __syncthreads();
  int g = t >> 5, ci = t & 31;
  float sm0 = sm[0], sm1 = sm[1], sm2 = sm[2], sm3 = sm[3];
  float si0 = sinv[0], si1 = sinv[1], si2 = sinv[2], si3 = sinv[3];
  float a0[4] = {}, a1[4] = {}, a2[4] = {}, a3[4] = {};
  for (int i = s0 + g; i < s1; i += 4) {
    int sidx = src[i];
    float4 e4 = *(const float4*)(el + (size_t)sidx * 4);
    float w0 = __expf(leaky(e4.x + erv.x) - sm0) * si0;
    float w1 = __expf(leaky(e4.y + erv.y) - sm1) * si1;
    float w2 = __expf(leaky(e4.z + erv.z) - sm2) * si2;
    float w3 = __expf(leaky(e4.w + erv.w) - sm3) * si3;
    half4v xv = *(const half4v*)(xh + (size_t)sidx * 128 + ci * 4);
#pragma unroll
    for (int c = 0; c < 4; ++c) {
      float xc = (float)xv[c];
      a0[c] += w0 * xc; a1[c] += w1 * xc; a2[c] += w2 * xc; a3[c] += w3 * xc;
    }
  }
#pragma unroll
  for (int c = 0; c < 4; ++c) {
    a0[c] += __shfl_xor(a0[c], 32);
    a1[c] += __shfl_xor(a1[c], 32);
    a2[c] += __shfl_xor(a2[c], 32);
    a3[c] += __shfl_xor(a3[c], 32);
  }
  if (w == 1 && lane < 32) {
#pragma unroll
    for (int c = 0; c < 4; ++c) {
      part[ci * 16 + c] = a0[c]; part[ci * 16 + 4 + c] = a1[c];
      part[ci * 16 + 8 + c] = a2[c]; part[ci * 16 + 12 + c] = a3[c];
    }
  }
  __syncthreads();
  if (w == 0 && lane < 32) {
    half4v o0, o1, o2, o3;
#pragma unroll
    for (int c = 0; c < 4; ++c) {
      o0[c] = (_Float16)(a0[c] + part[ci * 16 + c]);
      o1[c] = (_Float16)(a1[c] + part[ci * 16 + 4 + c]);
      o2[c] = (_Float16)(a2[c] + part[ci * 16 + 8 + c]);
      o3[c] = (_Float16)(a3[c] + part[ci * 16 + 12 + c]);
    }
    *(half4v*)(axh + ((size_t)n * 4 + 0) * 128 + ci * 4) = o0;
    *(half4v*)(axh + ((size_t)n * 4 + 1) * 128 + ci * 4) = o1;
    *(half4v*)(axh + ((size_t)n * 4 + 2) * 128 + ci * 4) = o2;
    *(half4v*)(axh + ((size_t)n * 4 + 3) * 128 + ci * 4) = o3;
  }
}

// layer-1 aggregation of h0 rows: axh1[n][h][0:256] = sum_e alpha[h] * h0[src_e]
__global__ __launch_bounds__(128) void agg1x_kernel(
    const int* __restrict__ src, const int* __restrict__ seg,
    const float* __restrict__ el, const float* __restrict__ er,
    const _Float16* __restrict__ h0, _Float16* __restrict__ axh1) {
  int n = blockIdx.x;
  int t = threadIdx.x, lane = t & 63, w = t >> 6;
  __shared__ float sm[4], sinv[4];
  __shared__ float part[1024];
  int s0 = seg[n], s1 = seg[n + 1];
  float4 erv = *(const float4*)(er + (size_t)n * 4);
  {
    float era = w ? erv.z : erv.x;
    float erb = w ? erv.w : erv.y;
    float ma = -1e30f, mb = -1e30f, sa = 0.f, sb = 0.f;
    for (int i = s0 + lane; i < s1; i += 64) {
      float4 e4 = *(const float4*)(el + (size_t)src[i] * 4);
      float ea = leaky((w ? e4.z : e4.x) + era);
      float eb = leaky((w ? e4.w : e4.y) + erb);
      float mna = fmaxf(ma, ea);
      sa = sa * __expf(ma - mna) + __expf(ea - mna); ma = mna;
      float mnb = fmaxf(mb, eb);
      sb = sb * __expf(mb - mnb) + __expf(eb - mnb); mb = mnb;
    }
    for (int off = 32; off; off >>= 1) {
      float mo = __shfl_xor(ma, off), so = __shfl_xor(sa, off);
      float mn = fmaxf(ma, mo);
      sa = sa * __expf(ma - mn) + so * __expf(mo - mn); ma = mn;
      mo = __shfl_xor(mb, off); so = __shfl_xor(sb, off);
      mn = fmaxf(mb, mo);
      sb = sb * __expf(mb - mn) + so * __expf(mo - mn); mb = mn;
    }
    if (lane == 0) {
      sm[2 * w] = ma; sm[2 * w + 1] = mb;
      sinv[2 * w] = 1.f / sa; sinv[2 * w + 1] = 1.f / sb;
    }
  }
  __syncthreads();
  int g = t >> 5, ci = t & 31;
  float sm0 = sm[0], sm1 = sm[1], sm2 = sm[2], sm3 = sm[3];
  float si0 = sinv[0], si1 = sinv[1], si2 = sinv[2], si3 = sinv[3];
  float a0[8] = {}, a1[8] = {}, a2[8] = {}, a3[8] = {};
  for (int i = s0 + g; i < s1; i += 4) {
    int sidx = src[i];
    float4 e4 = *(const float4*)(el + (size_t)sidx * 4);
    float w0 = __expf(leaky(e4.x + erv.x) - sm0) * si0;
    float w1 = __expf(leaky(e4.y + erv.y) - sm1) * si1;
    float w2 = __expf(leaky(e4.z + erv.z) - sm2) * si2;
    float w3 = __expf(leaky(e4.w + erv.w) - sm3) * si3;
    half8 xv = *(const half8*)(h0 + (size_t)sidx * 256 + ci * 8);
#pragma unroll
    for (int c = 0; c < 8; ++c) {
      float xc = (float)xv[c];
      a0[c] += w0 * xc; a1[c] += w1 * xc; a2[c] += w2 * xc; a3[c] += w3 * xc;
    }
  }
#pragma unroll
  for (int c = 0; c < 8; ++c) {
    a0[c] += __shfl_xor(a0[c], 32);
    a1[c] += __shfl_xor(a1[c], 32);
    a2[c] += __shfl_xor(a2[c], 32);
    a3[c] += __shfl_xor(a3[c], 32);
  }
  if (w == 1 && lane < 32) {
#pragma unroll
    for (int c = 0; c < 8; ++c) {
      part[ci * 32 + c] = a0[c]; part[ci * 32 + 8 + c] = a1[c];
      part[ci * 32 + 16 + c] = a2[c]; part[ci * 32 + 24 + c] = a3[c];
    }
  }
  __syncthreads();
  if (w == 0 && lane < 32) {
    half8 o0, o1, o2, o3;
#pragma unroll
    for (int c = 0; c < 8; ++c) {
      o0[c] = (_Float16)(a0[c] + part[ci * 32 + c]);
      o1[c] = (_Float16)(a1[c] + part[ci * 32 + 8 + c]);
      o2[c] = (_Float16)(a2[c] + part[ci * 32 + 16 + c]);
      o3[c] = (_Float16)(a3[c] + part[ci * 32 + 24 + c]);
    }
    *(half8*)(axh1 + ((size_t)n * 4 + 0) * 256 + ci * 8) = o0;
    *(half8*)(axh1 + ((size_t)n * 4 + 1) * 256 + ci * 8) = o1;
    *(half8*)(axh1 + ((size_t)n * 4 + 2) * 256 + ci * 8) = o2;
    *(half8*)(axh1 + ((size_t)n * 4 + 3) * 256 + ci * 8) = o3;
  }
}

// h0[m, h*64+d] = relu( axh[m,h,:] @ BT0[h*64+d, :] + b0 ), grid (4, 512)
__global__ __launch_bounds__(256) void gemm_h0_kernel(
    const _Float16* __restrict__ axh, const _Float16* __restrict__ BT,
    const float* __restrict__ b, _Float16* __restrict__ h0) {
  __shared__ _Float16 As[128 * 128];
  __shared__ _Float16 Bs[64 * 128];
  const int t = threadIdx.x, lane = t & 63, wid = t >> 6;
  const int h = blockIdx.x, m0 = blockIdx.y * 128;
  for (int i = 0; i < 8; ++i) {
    int c = t + 256 * i, row = c >> 4, j = c & 15;
    int sw = ((j ^ (row & 7)) << 3);
    *(half8*)(&As[row * 128 + sw]) =
        *(const half8*)(axh + ((size_t)(m0 + row) * 4 + h) * 128 + j * 8);
  }
  for (int i = 0; i < 4; ++i) {
    int c = t + 256 * i, row = c >> 4, j = c & 15;
    int sw = ((j ^ (row & 7)) << 3);
    *(half8*)(&Bs[row * 128 + sw]) =
        *(const half8*)(BT + (size_t)(h * 64 + row) * 128 + j * 8);
  }
  __syncthreads();
  const int wm = wid * 32;
  f32x4 acc[2][4] = {};
  for (int ks = 0; ks < 4; ++ks) {
    int kc = ks * 4 + (lane >> 4);
    half8 af[2], bf[4];
    for (int i = 0; i < 2; ++i) {
      int ra = wm + 16 * i + (lane & 15);
      af[i] = *(const half8*)(&As[ra * 128 + ((kc ^ (ra & 7)) << 3)]);
    }
    for (int j2 = 0; j2 < 4; ++j2) {
      int rb = 16 * j2 + (lane & 15);
      bf[j2] = *(const half8*)(&Bs[rb * 128 + ((kc ^ (rb & 7)) << 3)]);
    }
    for (int i = 0; i < 2; ++i)
      for (int j2 = 0; j2 < 4; ++j2)
        acc[i][j2] = __builtin_amdgcn_mfma_f32_16x16x32_f16(af[i], bf[j2], acc[i][j2], 0, 0, 0);
  }
  int quad = lane >> 4;
  for (int j2 = 0; j2 < 4; ++j2) {
    int gcol = h * 64 + 16 * j2 + (lane & 15);
    float bias = b[gcol];
    for (int i = 0; i < 2; ++i) {
      int r0 = m0 + wm + 16 * i + quad * 4;
      for (int r = 0; r < 4; ++r)
        h0[(size_t)(r0 + r) * 256 + gcol] = (_Float16)fmaxf(acc[i][j2][r] + bias, 0.f);
    }
  }
}

// out[m, 0:47] = log_softmax( axh1[m,:,:] (1024) @ BTs (1024 x 64, pre-scaled 0.25) + bmean )
__global__ __launch_bounds__(256) void gemm_out_kernel(
    const _Float16* __restrict__ axh1, const _Float16* __restrict__ BTs,
    const float* __restrict__ b1, float* __restrict__ out) {
  __shared__ _Float16 As[64 * 128];
  __shared__ _Float16 Bs[64 * 128];
  const int t = threadIdx.x, lane = t & 63, wid = t >> 6;
  const int m0 = blockIdx.x * 64;
  f32x4 acc[4] = {};
  for (int k0 = 0; k0 < 1024; k0 += 128) {
    for (int i = 0; i < 4; ++i) {
      int c = t + 256 * i, row = c >> 4, j = c & 15;
      int sw = ((j ^ (row & 7)) << 3);
      *(half8*)(&As[row * 128 + sw]) =
          *(const half8*)(axh1 + (size_t)(m0 + row) * 1024 + k0 + j * 8);
      *(half8*)(&Bs[row * 128 + sw]) =
          *(const half8*)(BTs + (size_t)row * 1024 + k0 + j * 8);
    }
    __syncthreads();
    const int wm = wid * 16;
    for (int ks = 0; ks < 4; ++ks) {
      int kc = ks * 4 + (lane >> 4);
      int ra = wm + (lane & 15);
      half8 af = *(const half8*)(&As[ra * 128 + ((kc ^ (ra & 7)) << 3)]);
      for (int j2 = 0; j2 < 4; ++j2) {
        int rb = 16 * j2 + (lane & 15);
        half8 bf = *(const half8*)(&Bs[rb * 128 + ((kc ^ (rb & 7)) << 3)]);
        acc[j2] = __builtin_amdgcn_mfma_f32_16x16x32_f16(af, bf, acc[j2], 0, 0, 0);
      }
    }
    __syncthreads();
  }
  int quad = lane >> 4, cl = lane & 15;
  float bm[3];
  for (int j2 = 0; j2 < 3; ++j2) {
    int col = 16 * j2 + cl;
    bm[j2] = (col < 47) ? 0.25f * (b1[col] + b1[col + 47] + b1[col + 94] + b1[col + 141]) : 0.f;
  }
  for (int r = 0; r < 4; ++r) {
    int row = m0 + wid * 16 + quad * 4 + r;
    float v[3];
    float mx = -1e30f;
    for (int j2 = 0; j2 < 3; ++j2) {
      int col = 16 * j2 + cl;
      v[j2] = acc[j2][r] + bm[j2];
      if (col < 47) mx = fmaxf(mx, v[j2]);
    }
    for (int off = 8; off; off >>= 1) mx = fmaxf(mx, __shfl_xor(mx, off));
    float s = 0.f;
    for (int j2 = 0; j2 < 3; ++j2) {
      int col = 16 * j2 + cl;
      if (col < 47) s += __expf(v[j2] - mx);
    }
    for (int off = 8; off; off >>= 1) s += __shfl_xor(s, off);
    float lse = mx + __logf(s);
    for (int j2 = 0; j2 < 3; ++j2) {
      int col = 16 * j2 + cl;
      if (col < 47) out[(size_t)row * 47 + col] = v[j2] - lse;
    }
  }
}

extern "C" void kernel_launch(void* const* d_in, const int* in_sizes, int n_in,
                              void* d_out, int out_size, void* d_ws, size_t ws_size,
                              hipStream_t stream) {
  const float* x   = (const float*)d_in[0];
  const int* src0  = (const int*)d_in[1];
  const int* dst0  = (const int*)d_in[2];
  const int* src1  = (const int*)d_in[3];
  const int* dst1  = (const int*)d_in[4];
  const float* Ws0 = (const float*)d_in[5];
  const float* Wd0 = (const float*)d_in[6];
  const float* al0 = (const float*)d_in[7];
  const float* ar0 = (const float*)d_in[8];
  const float* b0  = (const float*)d_in[9];
  const float* Ws1 = (const float*)d_in[10];
  const float* Wd1 = (const float*)d_in[11];
  const float* al1 = (const float*)d_in[12];
  const float* ar1 = (const float*)d_in[13];
  const float* b1  = (const float*)d_in[14];

  char* w = (char*)d_ws;
  auto alloc = [&](size_t bytes) {
    char* p = w;
    w += (bytes + 255) & ~(size_t)255;
    return p;
  };
  _Float16* xh   = (_Float16*)alloc((size_t)N_SRC0 * 128 * 2);   // 128 MB
  _Float16* axh  = (_Float16*)alloc((size_t)N_DST0 * 512 * 2);   // 67 MB
  _Float16* h0   = (_Float16*)alloc((size_t)N_DST0 * 256 * 2);   // 33.5 MB
  _Float16* axh1 = (_Float16*)alloc((size_t)N_DST1 * 1024 * 2);  // 16.8 MB
  float* el0     = (float*)alloc((size_t)N_SRC0 * 4 * 4);
  float* er0     = (float*)alloc((size_t)N_DST0 * 4 * 4);
  float* el1     = (float*)alloc((size_t)N_DST0 * 4 * 4);
  float* er1     = (float*)alloc((size_t)N_DST1 * 4 * 4);
  int* seg0      = (int*)alloc((size_t)(N_DST0 + 1) * 4);
  int* seg1      = (int*)alloc((size_t)(N_DST1 + 1) * 4);
  _Float16* BT0  = (_Float16*)alloc(256 * 128 * 2);
  _Float16* BTs  = (_Float16*)alloc(64 * 1024 * 2);
  float* wl0     = (float*)alloc(128 * 4 * 4);
  float* wr0     = (float*)alloc(128 * 4 * 4);
  float* wl1     = (float*)alloc(256 * 4 * 4);
  float* wr1     = (float*)alloc(256 * 4 * 4);

  collapse_kernel<<<2, 256, 0, stream>>>(Ws0, al0, wl0, 128, 64);
  collapse_kernel<<<2, 256, 0, stream>>>(Wd0, ar0, wr0, 128, 64);
  collapse_kernel<<<4, 256, 0, stream>>>(Ws1, al1, wl1, 256, 47);
  collapse_kernel<<<4, 256, 0, stream>>>(Wd1, ar1, wr1, 256, 47);
  transposeW_kernel<<<128, 256, 0, stream>>>(Ws0, BT0, 128, 256);
  wstack_kernel<<<256, 256, 0, stream>>>(Ws1, BTs);
  seg_starts_kernel<<<(E0 + 1 + 255) / 256, 256, 0, stream>>>(dst0, E0, N_DST0, seg0);
  seg_starts_kernel<<<(E1 + 1 + 255) / 256, 256, 0, stream>>>(dst1, E1, N_DST1, seg1);
  cvt_el_er_kernel<<<N_SRC0 / 4, 256, 0, stream>>>(x, xh, wl0, wr0, el0, er0, N_SRC0, N_DST0);
  agg0x_kernel<<<N_DST0, 128, 0, stream>>>(src0, seg0, el0, er0, xh, axh);
  gemm_h0_kernel<<<dim3(4, N_DST0 / 128), 256, 0, stream>>>(axh, BT0, b0, h0);
  el_er1_kernel<<<N_DST0 / 4, 256, 0, stream>>>(h0, wl1, wr1, el1, er1, N_DST0, N_DST1);
  agg1x_kernel<<<N_DST1, 128, 0, stream>>>(src1, seg1, el1, er1, h0, axh1);
  gemm_out_kernel<<<N_DST1 / 64, 256, 0, stream>>>(axh1, BTs, b1, (float*)d_out);
}